// Round 6
// baseline (1321.205 us; speedup 1.0000x reference)
//
#include <hip/hip_runtime.h>
#include <cstdint>

typedef unsigned short u16;
typedef unsigned int   u32;
typedef unsigned long long u64;

typedef _Float16 f16x2 __attribute__((ext_vector_type(2)));
typedef _Float16 f16x8 __attribute__((ext_vector_type(8)));
typedef float    f32x4 __attribute__((ext_vector_type(4)));

#define BM 128
#define BN 128
#define BK 64

// pack two f32 into fp16x2 bits (RTZ exact: inputs are fp16-representable)
__device__ __forceinline__ u32 cvt_pk(float a, float b) {
    return __builtin_bit_cast(u32, __builtin_amdgcn_cvt_pkrtz(a, b));
}

// s_waitcnt imm: vmcnt[3:0]|[15:14], expcnt[6:4], lgkmcnt[11:8].
// 0xC07F = vmcnt(63) expcnt(7) lgkmcnt(0)  -> wait LDS ops only.
#define WAIT_LGKM0() __builtin_amdgcn_s_waitcnt(0xC07F)

// Fixed problem: M=8192, N=4096, K=4096, G=32 (gsize=128)
// x/scales/bias/y are f32 buffers (harness promotes fp16; values fp16-exact).
// LDS: XOR-swizzled granules (round-5 layout, 0 bank conflicts).
// K-loop: software-pipelined register prefetch (2 tile buffers), raw
// s_barrier + lgkm-only waits so prefetch loads stay in flight across
// barriers (ds_writes drained by explicit lgkmcnt(0); ds_reads are all
// consumed by MFMAs before the tail barrier; prefetch targets VGPRs only).
__global__ __launch_bounds__(256, 3) void gptq_gemm_kernel(
    const float* __restrict__ X,    // [M, K] f32
    const int* __restrict__ QW,     // [N, K/8] int32, nibbles LSB-first along K
    const int* __restrict__ QZ,     // [G, N/8] int32, nibbles LSB-first along N
    const float* __restrict__ SC,   // [G, N] f32
    const float* __restrict__ BIAS, // [N] f32
    float* __restrict__ Y)          // [M, N] f32
{
    constexpr int M = 8192, N = 4096, K = 4096, G = 32;
    constexpr int KB = K / 8;

    __shared__ __align__(16) u16 Alds[BM * BK];
    __shared__ __align__(16) u16 Blds[BN * BK];

    const int tid  = threadIdx.x;
    const int lane = tid & 63;
    const int wid  = tid >> 6;

    // grid flipped: x = n-block (32, fastest) so concurrent blocks share X rows
    const int n0 = blockIdx.x * BN;
    const int m0 = blockIdx.y * BM;

    f32x4 acc[4][4];
#pragma unroll
    for (int i = 0; i < 4; i++)
#pragma unroll
        for (int j = 0; j < 4; j++)
            acc[i][j] = (f32x4){0.f, 0.f, 0.f, 0.f};

    const int wm = (wid >> 1) * 64;
    const int wn = (wid & 1) * 64;

    // A staging map
    const int lrowA = tid >> 3;
    const float* gA = X + (u64)(m0 + lrowA) * K + (tid & 7) * 8;
    const int sA = ((tid & 7) ^ (lrowA & 7)) * 8;

    // B staging map
    const int nl  = tid >> 1;
    const int kq0 = (tid & 1) * 4;
    const int nglob = n0 + nl;
    const int* qrow = QW + (u64)nglob * KB;
    const int nl7 = nl & 7;

    // MFMA fragment addressing
    const int fr   = lane & 15;
    const int quad = lane >> 4;
    const int fr7  = fr & 7;

    // group-constant streams (prefetched one group ahead)
    const float* scp = SC + nglob;
    const int*   zwp = QZ + (nglob >> 3);
    const int    zsh = (nglob & 7) * 4;
    float sf_c = scp[0];
    int   zw_c = zwp[0];
    float sf_n = scp[N];
    int   zw_n = zwp[N / 8];

    float4 avA[8]; int4 qA;   // even-tile buffer
    float4 avB[8]; int4 qB;   // odd-tile buffer

#define LOAD_TILE(AV, QQ, KT) do {                                   \
        const float* pa_ = gA + (KT);                                \
        AV[0] = *(const float4*)(pa_);                               \
        AV[1] = *(const float4*)(pa_ + 4);                           \
        AV[2] = *(const float4*)(pa_ + (u64)32 * K);                 \
        AV[3] = *(const float4*)(pa_ + (u64)32 * K + 4);             \
        AV[4] = *(const float4*)(pa_ + (u64)64 * K);                 \
        AV[5] = *(const float4*)(pa_ + (u64)64 * K + 4);             \
        AV[6] = *(const float4*)(pa_ + (u64)96 * K);                 \
        AV[7] = *(const float4*)(pa_ + (u64)96 * K + 4);             \
        QQ = *(const int4*)(qrow + ((KT) >> 3) + kq0);               \
    } while (0)

#define STAGE_TILE(AV, QQ) do {                                      \
        _Pragma("unroll")                                            \
        for (int i_ = 0; i_ < 4; i_++) {                             \
            const float4 f0_ = AV[2 * i_], f1_ = AV[2 * i_ + 1];     \
            uint4 w_;                                                \
            w_.x = cvt_pk(f0_.x, f1_.x);                             \
            w_.y = cvt_pk(f0_.y, f1_.y);                             \
            w_.z = cvt_pk(f0_.z, f1_.z);                             \
            w_.w = cvt_pk(f0_.w, f1_.w);                             \
            *(uint4*)(&Alds[(i_ * 32 + lrowA) * 64 + sA]) = w_;      \
        }                                                            \
        const int qv_[4] = {QQ.x, QQ.y, QQ.z, QQ.w};                 \
        _Pragma("unroll")                                            \
        for (int c_ = 0; c_ < 4; c_++) {                             \
            const u32 q_  = (u32)qv_[c_];                            \
            const u32 b0_ = (q_ & 0x000F000Fu) | 0x64006400u;        \
            const u32 b1_ = ((q_ >> 4) & 0x000F000Fu) | 0x64006400u; \
            const u32 b2_ = ((q_ >> 8) & 0x000F000Fu) | 0x64006400u; \
            const u32 b3_ = ((q_ >> 12) & 0x000F000Fu) | 0x64006400u;\
            const f16x2 w0_ = (__builtin_bit_cast(f16x2, b0_) - cz) * cs; \
            const f16x2 w1_ = (__builtin_bit_cast(f16x2, b1_) - cz) * cs; \
            const f16x2 w2_ = (__builtin_bit_cast(f16x2, b2_) - cz) * cs; \
            const f16x2 w3_ = (__builtin_bit_cast(f16x2, b3_) - cz) * cs; \
            uint4 w_;                                                \
            w_.x = __builtin_bit_cast(u32, w0_);                     \
            w_.y = __builtin_bit_cast(u32, w1_);                     \
            w_.z = __builtin_bit_cast(u32, w2_);                     \
            w_.w = __builtin_bit_cast(u32, w3_);                     \
            *(uint4*)(&Blds[nl * 64 + (((kq0 + c_) ^ nl7) * 8)]) = w_; \
        }                                                            \
    } while (0)

#define MFMA_TILE() do {                                             \
        _Pragma("unroll")                                            \
        for (int ks_ = 0; ks_ < 2; ks_++) {                          \
            const int gsw_ = ((ks_ * 4 + quad) ^ fr7) * 8;           \
            f16x8 af_[4], bf_[4];                                    \
            _Pragma("unroll")                                        \
            for (int i_ = 0; i_ < 4; i_++)                           \
                af_[i_] = *(const f16x8*)(&Alds[(wm + i_ * 16 + fr) * 64 + gsw_]); \
            _Pragma("unroll")                                        \
            for (int i_ = 0; i_ < 4; i_++)                           \
                bf_[i_] = *(const f16x8*)(&Blds[(wn + i_ * 16 + fr) * 64 + gsw_]); \
            _Pragma("unroll")                                        \
            for (int mi_ = 0; mi_ < 4; mi_++)                        \
                _Pragma("unroll")                                    \
                for (int ni_ = 0; ni_ < 4; ni_++)                    \
                    acc[mi_][ni_] = __builtin_amdgcn_mfma_f32_16x16x32_f16( \
                        af_[mi_], bf_[ni_], acc[mi_][ni_], 0, 0, 0); \
        }                                                            \
    } while (0)

    LOAD_TILE(avA, qA, 0);
    LOAD_TILE(avB, qB, 64);

    for (int g = 0; g < G; ++g) {
        const _Float16 hs = (_Float16)sf_c;
        const _Float16 hz = (_Float16)(float)(1024 + ((zw_c >> zsh) & 0xF));
        const f16x2 cs = {hs, hs};
        const f16x2 cz = {hz, hz};
        const int ktA = g * 128;

        // ---- phase 0: consume bufA (tile 2g), prefetch bufA <- tile 2g+2 ----
        STAGE_TILE(avA, qA);
        { const int ktn = (ktA + 128 < K) ? (ktA + 128) : ktA;
          LOAD_TILE(avA, qA, ktn); }
        WAIT_LGKM0();
        __builtin_amdgcn_s_barrier();
        MFMA_TILE();
        __builtin_amdgcn_s_barrier();

        // ---- phase 1: consume bufB (tile 2g+1), prefetch bufB <- tile 2g+3 ----
        STAGE_TILE(avB, qB);
        { const int ktn = (ktA + 192 < K) ? (ktA + 192) : (ktA + 64);
          LOAD_TILE(avB, qB, ktn); }
        // rotate group constants (cs/cz already hold group g's values)
        sf_c = sf_n; zw_c = zw_n;
        { const int gi = (g + 2 < G) ? (g + 2) : (G - 1);
          sf_n = scp[(u64)gi * N]; zw_n = zwp[(u64)gi * (N / 8)]; }
        WAIT_LGKM0();
        __builtin_amdgcn_s_barrier();
        MFMA_TILE();
        __builtin_amdgcn_s_barrier();
    }

    // ---- epilogue: + bias, store f32. C/D map: col=lane&15, row=quad*4+reg ----
    const int cn  = lane & 15;
    const int q4r = quad * 4;
#pragma unroll
    for (int ni = 0; ni < 4; ni++) {
        const int col = n0 + wn + ni * 16 + cn;
        const float bz = BIAS[col];
#pragma unroll
        for (int mi = 0; mi < 4; mi++) {
            const int rbase = m0 + wm + mi * 16 + q4r;
#pragma unroll
            for (int r = 0; r < 4; r++) {
                Y[(u64)(rbase + r) * N + col] = acc[mi][ni][r] + bz;
            }
        }
    }
}

extern "C" void kernel_launch(void* const* d_in, const int* in_sizes, int n_in,
                              void* d_out, int out_size, void* d_ws, size_t ws_size,
                              hipStream_t stream) {
    const float* X    = (const float*)d_in[0];   // x       [2,4096,4096] f32
    const int*   QW   = (const int*)d_in[1];     // qweight [4096,512] int32
    const int*   QZ   = (const int*)d_in[2];     // qzeros  [32,512] int32
    const float* SC   = (const float*)d_in[3];   // scales  [32,4096] f32
    const float* BIAS = (const float*)d_in[4];   // bias    [4096] f32
    float* Y = (float*)d_out;                    // [8192,4096] f32

    dim3 grid(32, 64, 1);   // x = N/128 (fastest), y = M/128
    gptq_gemm_kernel<<<grid, 256, 0, stream>>>(X, QW, QZ, SC, BIAS, Y);
}